// Round 4
// baseline (230.877 us; speedup 1.0000x reference)
//
#include <hip/hip_runtime.h>

// ShortConvolution: depthwise causal conv1d (K=4) + SiLU
// x: (B=4, T=4096, D=2048) fp32, weight: (D, K) fp32, out: (B, T, D) fp32
// y[b,t,d] = silu( sum_k w[d,k] * x[b, t-3+k, d] )   (x[t<0] = 0)
//
// R3: async LDS staging. R1/R2 register-batching was defeated twice by
// IR-level load sinking (VGPR stayed 32/36, one load in flight, vmcnt(0)
// per step also draining stores -> 2.8 TB/s latency-bound).
// global_load_lds is side-effecting (writes LDS) so it cannot be sunk:
// 11 async 16B loads issue back-to-back per wave, drain once at the
// barrier; compute/store phase touches only lgkmcnt. 44 KB LDS -> 3
// blocks/CU -> 132 KB in flight per CU during staging (need ~9 KB).

#define B_DIM 4
#define T_DIM 4096
#define D_DIM 2048
#define K_DIM 4
#define TC    8                 // timesteps per block
#define DH    1024              // D-columns per block (half row)
#define NROWS (TC + K_DIM - 1)  // 11 staged rows

typedef float f4_t __attribute__((ext_vector_type(4)));

__global__ __launch_bounds__(256) void shortconv_silu_kernel(
    const float* __restrict__ x,
    const float* __restrict__ w,
    float* __restrict__ out)
{
    __shared__ float lds[NROWS * DH];       // 11 * 4 KB = 44 KB

    const int n_chunks = T_DIM / TC;        // 512
    const int half = blockIdx.x & 1;        // which D half
    const int bc   = blockIdx.x >> 1;
    const int b    = bc / n_chunks;
    const int c    = bc % n_chunks;
    const int t0   = c * TC;
    const int tid  = threadIdx.x;           // 0..255, one f4 column each
    const int col0 = half * DH + tid * 4;   // first of 4 channels

    const float* xbase = x + ((size_t)b * T_DIM) * D_DIM + col0;

    // ---- Phase 1: async-stage NROWS rows of x into LDS ----
    // LDS dest = wave-uniform base + lane*16 (required by global_load_lds):
    // row r at lds + r*DH, thread tid at +tid*4 floats -> contiguous. OK.
    if (c == 0) {
        // rows 0..2 are t = -3..-1 -> zeros
        f4_t z = (f4_t)0.f;
        *(f4_t*)(lds + 0 * DH + tid * 4) = z;
        *(f4_t*)(lds + 1 * DH + tid * 4) = z;
        *(f4_t*)(lds + 2 * DH + tid * 4) = z;
#pragma unroll
        for (int r = 3; r < NROWS; ++r) {
            __builtin_amdgcn_global_load_lds(
                (const __attribute__((address_space(1))) void*)(xbase + (size_t)(t0 + r - 3) * D_DIM),
                (__attribute__((address_space(3))) void*)(lds + r * DH + tid * 4),
                16, 0, 0);
        }
    } else {
#pragma unroll
        for (int r = 0; r < NROWS; ++r) {
            __builtin_amdgcn_global_load_lds(
                (const __attribute__((address_space(1))) void*)(xbase + (size_t)(t0 + r - 3) * D_DIM),
                (__attribute__((address_space(3))) void*)(lds + r * DH + tid * 4),
                16, 0, 0);
        }
    }

    // Per-thread weights: 4 channels x 4 taps = 16 consecutive floats ((D,K) row-major)
    const f4_t q0 = *(const f4_t*)(w + (size_t)(col0 + 0) * K_DIM);
    const f4_t q1 = *(const f4_t*)(w + (size_t)(col0 + 1) * K_DIM);
    const f4_t q2 = *(const f4_t*)(w + (size_t)(col0 + 2) * K_DIM);
    const f4_t q3 = *(const f4_t*)(w + (size_t)(col0 + 3) * K_DIM);

    __syncthreads();

    // ---- Phase 2: sliding window over LDS rows, compute + store ----
    const f4_t* lv = (const f4_t*)lds;      // row stride DH/4 = 256 f4
    f4_t w0 = lv[0 * (DH / 4) + tid];
    f4_t w1 = lv[1 * (DH / 4) + tid];
    f4_t w2 = lv[2 * (DH / 4) + tid];

    float* obase = out + ((size_t)b * T_DIM + t0) * D_DIM + col0;

#pragma unroll
    for (int i = 0; i < TC; ++i) {
        f4_t w3 = lv[(i + 3) * (DH / 4) + tid];

        f4_t y;
        y.x = q0.x * w0.x + q0.y * w1.x + q0.z * w2.x + q0.w * w3.x;
        y.y = q1.x * w0.y + q1.y * w1.y + q1.z * w2.y + q1.w * w3.y;
        y.z = q2.x * w0.z + q2.y * w1.z + q2.z * w2.z + q2.w * w3.z;
        y.w = q3.x * w0.w + q3.y * w1.w + q3.z * w2.w + q3.w * w3.w;

        // SiLU: y / (1 + exp(-y))
        y.x = y.x / (1.f + __expf(-y.x));
        y.y = y.y / (1.f + __expf(-y.y));
        y.z = y.z / (1.f + __expf(-y.z));
        y.w = y.w / (1.f + __expf(-y.w));

        __builtin_nontemporal_store(y, (f4_t*)(obase + (size_t)i * D_DIM));

        w0 = w1;
        w1 = w2;
        w2 = w3;
    }
}

extern "C" void kernel_launch(void* const* d_in, const int* in_sizes, int n_in,
                              void* d_out, int out_size, void* d_ws, size_t ws_size,
                              hipStream_t stream) {
    const float* x = (const float*)d_in[0];
    const float* w = (const float*)d_in[1];
    float* out = (float*)d_out;

    const int n_chunks = T_DIM / TC;              // 512
    dim3 grid(B_DIM * n_chunks * 2);              // 4096 blocks (x2 D-halves)
    dim3 block(256);
    shortconv_silu_kernel<<<grid, block, 0, stream>>>(x, w, out);
}